// Round 11
// baseline (133.136 us; speedup 1.0000x reference)
//
#include <hip/hip_runtime.h>
#include <hip/hip_bf16.h>

#define DIN 128
#define DOUT 128
#define ALPHA 0.2f
#define EPS 1e-15f
#define INV_SCALE 0.1f
#define KB 16
#define CAP 64   // padded bucket capacity; max degree ~28 for Binomial(600K,1/50K)

__device__ inline unsigned short f2b(float f) {
    unsigned int u = __float_as_uint(f);
    unsigned int r = (u + 0x7fffu + ((u >> 16) & 1u)) >> 16;   // RNE
    return (unsigned short)r;
}
__device__ inline float blo(unsigned int v) { return __uint_as_float(v << 16); }
__device__ inline float bhi(unsigned int v) { return __uint_as_float(v & 0xffff0000u); }

// ---------------------------------------------------------------------------
// K1: h = x @ W (fp32 accum, bf16 store), s1 = h.a[0:128], s2 = h.a[128:256].
// R7 structure (tripwire-green 7/7). Preamble zeroes cursor[] and wsum[].
// ---------------------------------------------------------------------------
__global__ __launch_bounds__(256) void gemm_s_kernel(
    const float* __restrict__ x, const float* __restrict__ W,
    const float* __restrict__ a, unsigned short* __restrict__ hb,
    float* __restrict__ s1, float* __restrict__ s2,
    int* __restrict__ cursor, long long* __restrict__ wsum, int N)
{
    __shared__ float xT[128 * 32];        // [k][r] 16 KB
    __shared__ float Wc[2][KB * 128];     // [kk][c] 2 x 8 KB
    const int t = threadIdx.x;
    const int row0 = blockIdx.x * 32;

    {   // fused zero of cursor + wsum (grid 1563*256 >= N)
        int g0 = blockIdx.x * 256 + t;
        if (g0 < N) { cursor[g0] = 0; wsum[g0] = 0; }
    }

    // Load x tile transposed -> LDS
#pragma unroll
    for (int it = 0; it < 4; ++it) {
        int i = t + it * 256;
        int r = i & 31;
        int k4 = i >> 5;
        int row = row0 + r;
        float4 v = make_float4(0.f, 0.f, 0.f, 0.f);
        if (row < N) v = *(const float4*)(x + (size_t)row * DIN + k4 * 4);
        xT[(k4 * 4 + 0) * 32 + r] = v.x;
        xT[(k4 * 4 + 1) * 32 + r] = v.y;
        xT[(k4 * 4 + 2) * 32 + r] = v.z;
        xT[(k4 * 4 + 3) * 32 + r] = v.w;
    }

    auto stage = [&](int buf, int k0) {
        const float4* Wg = (const float4*)(W + k0 * 128);
        float4* Wd = (float4*)Wc[buf];
        Wd[t] = Wg[t];
        Wd[t + 256] = Wg[t + 256];
    };
    stage(0, 0);
    __syncthreads();

    const int cg = t & 31;
    const int rg = t >> 5;
    const int c0 = cg * 4;

    float acc[4][4];
#pragma unroll
    for (int i = 0; i < 4; ++i)
#pragma unroll
        for (int j = 0; j < 4; ++j) acc[i][j] = 0.f;

    const int NCH = 128 / KB;   // 8
    for (int c = 0; c < NCH; ++c) {
        if (c + 1 < NCH) stage((c + 1) & 1, (c + 1) * KB);
        const float* Wb = Wc[c & 1];
        const int kbase = c * KB;
#pragma unroll
        for (int kk = 0; kk < KB; ++kk) {
            float4 wv = *(const float4*)(Wb + kk * 128 + c0);
            float4 xv = *(const float4*)(xT + (kbase + kk) * 32 + rg * 4);
            float xr[4] = {xv.x, xv.y, xv.z, xv.w};
            float wr[4] = {wv.x, wv.y, wv.z, wv.w};
#pragma unroll
            for (int i = 0; i < 4; ++i)
#pragma unroll
                for (int j = 0; j < 4; ++j) acc[i][j] = fmaf(xr[i], wr[j], acc[i][j]);
        }
        __syncthreads();
    }

    const float4 a1 = *(const float4*)(a + c0);
    const float4 a2 = *(const float4*)(a + 128 + c0);

#pragma unroll
    for (int ri = 0; ri < 4; ++ri) {
        int row = row0 + rg * 4 + ri;
        float p1 = acc[ri][0] * a1.x + acc[ri][1] * a1.y + acc[ri][2] * a1.z + acc[ri][3] * a1.w;
        float p2 = acc[ri][0] * a2.x + acc[ri][1] * a2.y + acc[ri][2] * a2.z + acc[ri][3] * a2.w;
#pragma unroll
        for (int m = 16; m >= 1; m >>= 1) {
            p1 += __shfl_xor(p1, m, 64);
            p2 += __shfl_xor(p2, m, 64);
        }
        if (row < N) {
            ushort4 hv;
            hv.x = f2b(acc[ri][0]); hv.y = f2b(acc[ri][1]);
            hv.z = f2b(acc[ri][2]); hv.w = f2b(acc[ri][3]);
            *(ushort4*)(hb + (size_t)row * DOUT + c0) = hv;
            if (cg == 0) { s1[row] = p1; s2[row] = p2; }
        }
    }
}

// ---------------------------------------------------------------------------
// K2: per-edge weight; scatter (dst, w) into padded per-node buckets AND
// accumulate wsum[s] as int64 fixed-point (2^-36) atomics. Integer atomics
// are associative => wsum is order-invariant => deterministic.
// ---------------------------------------------------------------------------
__global__ void scatter_kernel(
    const int* __restrict__ src, const int* __restrict__ dst,
    const float* __restrict__ s1, const float* __restrict__ s2,
    int* __restrict__ cursor, long long* __restrict__ wsum,
    int2* __restrict__ bucket, int E)
{
    int i = blockIdx.x * blockDim.x + threadIdx.x;
    int stride = gridDim.x * blockDim.x;
    for (; i < E; i += stride) {
        int s = src[i], d = dst[i];
        float logit = s1[s] + s2[d];
        float lr = (logit > 0.f) ? logit : ALPHA * logit;
        float wv = expf(-lr);
        atomicAdd((unsigned long long*)&wsum[s],
                  (unsigned long long)(long long)(wv * 0x1p36f));
        int pos = atomicAdd(&cursor[s], 1);
        if (pos < CAP) bucket[(size_t)s * CAP + pos] = make_int2(d, __float_as_int(wv));
    }
}

// ---------------------------------------------------------------------------
// K3: one wave per node; bf16 h gathers, 8x/2x unrolled for MLP.
// ax/ay accumulate int32 TERMS (single v_cvt_i32_f32, scale 2^24) into int64
// accumulators (2-op adds): exact integer sums => bucket-order-invariant =>
// deterministic. Term bound: w*|h|*2^24 <= ~5e8 < 2^31. Truncation error
// <= cnt*2^-24 ~ 1e-6 absolute; worst realistic amplification 1/ws ~ 100x
// -> ~1e-4, negligible vs bf16's 2e-3. ws comes exact from scatter's int64.
// ---------------------------------------------------------------------------
#define EDGE(k)                                                          \
    {                                                                    \
        float wvs = __int_as_float(e##k.y) * 0x1p24f;                    \
        axi += (long long)(int)(wvs * blo(v##k));                        \
        ayi += (long long)(int)(wvs * bhi(v##k));                        \
    }

__global__ __launch_bounds__(256) void aggregate_kernel(
    const unsigned int* __restrict__ hb, const int* __restrict__ cursor,
    const long long* __restrict__ wsum, const int2* __restrict__ bucket,
    float* __restrict__ out, int N)
{
    const int node = blockIdx.x * 4 + (threadIdx.x >> 6);
    const int lane = threadIdx.x & 63;
    if (node >= N) return;

    const int2* __restrict__ csr = bucket + (size_t)node * CAP;
    const int cnt = min(cursor[node], CAP);

    long long axi = 0, ayi = 0;
    int i = 0;
    for (; i + 8 <= cnt; i += 8) {
        int2 e0 = csr[i + 0], e1 = csr[i + 1], e2 = csr[i + 2], e3 = csr[i + 3];
        int2 e4 = csr[i + 4], e5 = csr[i + 5], e6 = csr[i + 6], e7 = csr[i + 7];
        unsigned int v0 = hb[(size_t)e0.x * 64 + lane];
        unsigned int v1 = hb[(size_t)e1.x * 64 + lane];
        unsigned int v2 = hb[(size_t)e2.x * 64 + lane];
        unsigned int v3 = hb[(size_t)e3.x * 64 + lane];
        unsigned int v4 = hb[(size_t)e4.x * 64 + lane];
        unsigned int v5 = hb[(size_t)e5.x * 64 + lane];
        unsigned int v6 = hb[(size_t)e6.x * 64 + lane];
        unsigned int v7 = hb[(size_t)e7.x * 64 + lane];
        EDGE(0) EDGE(1) EDGE(2) EDGE(3) EDGE(4) EDGE(5) EDGE(6) EDGE(7)
    }
    for (; i + 2 <= cnt; i += 2) {
        int2 e0 = csr[i + 0], e1 = csr[i + 1];
        unsigned int v0 = hb[(size_t)e0.x * 64 + lane];
        unsigned int v1 = hb[(size_t)e1.x * 64 + lane];
        EDGE(0) EDGE(1)
    }
    if (i < cnt) {
        int2 e0 = csr[i];
        unsigned int v0 = hb[(size_t)e0.x * 64 + lane];
        EDGE(0)
    }

    float ws = (float)wsum[node] * 0x1p-36f;
    float ax = (float)axi * 0x1p-24f;
    float ay = (float)ayi * 0x1p-24f;

    float inv = 1.f / fmaxf(ws, EPS);
    float ux = fmaxf(ax * inv, 0.f) * INV_SCALE;
    float uy = fmaxf(ay * inv, 0.f) * INV_SCALE;

    float nsq = ux * ux + uy * uy;
#pragma unroll
    for (int m = 32; m >= 1; m >>= 1) nsq += __shfl_xor(nsq, m, 64);
    float norm = fmaxf(sqrtf(nsq), EPS);
    float scale = tanhf(norm) / norm;

    *(float2*)(out + (size_t)node * DOUT + lane * 2) = make_float2(ux * scale, uy * scale);
}

// ---------------------------------------------------------------------------
extern "C" void kernel_launch(void* const* d_in, const int* in_sizes, int n_in,
                              void* d_out, int out_size, void* d_ws, size_t ws_size,
                              hipStream_t stream)
{
    const float* x = (const float*)d_in[0];
    const float* W = (const float*)d_in[1];
    const float* a = (const float*)d_in[2];
    const int* edge = (const int*)d_in[3];
    const int N = in_sizes[0] / DIN;
    const int E = in_sizes[3] / 2;
    const int* src = edge;
    const int* dst = edge + E;
    float* out = (float*)d_out;

    char* w = (char*)d_ws;
    size_t off = 0;
    auto take = [&](size_t bytes) -> void* {
        void* p = (void*)(w + off);
        off += (bytes + 255) & ~(size_t)255;
        return p;
    };
    unsigned short* hb = (unsigned short*)take((size_t)N * DOUT * 2);  // 12.8 MB bf16
    float*     s1     = (float*)    take((size_t)N * 4);
    float*     s2     = (float*)    take((size_t)N * 4);
    int*       cursor = (int*)      take((size_t)N * 4);
    long long* wsum   = (long long*)take((size_t)N * 8);
    int2*      bucket = (int2*)     take((size_t)N * CAP * 8);         // 25.6 MB
    (void)ws_size; (void)n_in; (void)out_size;

    hipLaunchKernelGGL(gemm_s_kernel, dim3((N + 31) / 32), dim3(256), 0, stream,
                       x, W, a, hb, s1, s2, cursor, wsum, N);
    hipLaunchKernelGGL(scatter_kernel, dim3(1024), dim3(256), 0, stream,
                       src, dst, s1, s2, cursor, wsum, bucket, E);
    hipLaunchKernelGGL(aggregate_kernel, dim3((N + 3) / 4), dim3(256), 0, stream,
                       (const unsigned int*)hb, cursor, wsum, bucket, out, N);
}

// Round 12
// 110.273 us; speedup vs baseline: 1.2073x; 1.2073x over previous
//
#include <hip/hip_runtime.h>
#include <hip/hip_bf16.h>

#define DIN 128
#define DOUT 128
#define ALPHA 0.2f
#define EPS 1e-15f
#define INV_SCALE 0.1f
#define KB 16
#define CAP 64   // padded bucket capacity; max degree ~28 for Binomial(600K,1/50K)

__device__ inline unsigned short f2b(float f) {
    unsigned int u = __float_as_uint(f);
    unsigned int r = (u + 0x7fffu + ((u >> 16) & 1u)) >> 16;   // RNE
    return (unsigned short)r;
}
__device__ inline float blo(unsigned int v) { return __uint_as_float(v << 16); }
__device__ inline float bhi(unsigned int v) { return __uint_as_float(v & 0xffff0000u); }

// ---------------------------------------------------------------------------
// K1: h = x @ W (fp32 accum, bf16 store), s1 = h.a[0:128], s2 = h.a[128:256].
// R7 structure (tripwire-green). Preamble zeroes cursor[].
// ---------------------------------------------------------------------------
__global__ __launch_bounds__(256) void gemm_s_kernel(
    const float* __restrict__ x, const float* __restrict__ W,
    const float* __restrict__ a, unsigned short* __restrict__ hb,
    float* __restrict__ s1, float* __restrict__ s2,
    int* __restrict__ cursor, int N)
{
    __shared__ float xT[128 * 32];        // [k][r] 16 KB
    __shared__ float Wc[2][KB * 128];     // [kk][c] 2 x 8 KB
    const int t = threadIdx.x;
    const int row0 = blockIdx.x * 32;

    {   // fused cursor zero (grid 1563*256 >= N)
        int g0 = blockIdx.x * 256 + t;
        if (g0 < N) cursor[g0] = 0;
    }

    // Load x tile transposed -> LDS
#pragma unroll
    for (int it = 0; it < 4; ++it) {
        int i = t + it * 256;
        int r = i & 31;
        int k4 = i >> 5;
        int row = row0 + r;
        float4 v = make_float4(0.f, 0.f, 0.f, 0.f);
        if (row < N) v = *(const float4*)(x + (size_t)row * DIN + k4 * 4);
        xT[(k4 * 4 + 0) * 32 + r] = v.x;
        xT[(k4 * 4 + 1) * 32 + r] = v.y;
        xT[(k4 * 4 + 2) * 32 + r] = v.z;
        xT[(k4 * 4 + 3) * 32 + r] = v.w;
    }

    auto stage = [&](int buf, int k0) {
        const float4* Wg = (const float4*)(W + k0 * 128);
        float4* Wd = (float4*)Wc[buf];
        Wd[t] = Wg[t];
        Wd[t + 256] = Wg[t + 256];
    };
    stage(0, 0);
    __syncthreads();

    const int cg = t & 31;
    const int rg = t >> 5;
    const int c0 = cg * 4;

    float acc[4][4];
#pragma unroll
    for (int i = 0; i < 4; ++i)
#pragma unroll
        for (int j = 0; j < 4; ++j) acc[i][j] = 0.f;

    const int NCH = 128 / KB;   // 8
    for (int c = 0; c < NCH; ++c) {
        if (c + 1 < NCH) stage((c + 1) & 1, (c + 1) * KB);
        const float* Wb = Wc[c & 1];
        const int kbase = c * KB;
#pragma unroll
        for (int kk = 0; kk < KB; ++kk) {
            float4 wv = *(const float4*)(Wb + kk * 128 + c0);
            float4 xv = *(const float4*)(xT + (kbase + kk) * 32 + rg * 4);
            float xr[4] = {xv.x, xv.y, xv.z, xv.w};
            float wr[4] = {wv.x, wv.y, wv.z, wv.w};
#pragma unroll
            for (int i = 0; i < 4; ++i)
#pragma unroll
                for (int j = 0; j < 4; ++j) acc[i][j] = fmaf(xr[i], wr[j], acc[i][j]);
        }
        __syncthreads();
    }

    const float4 a1 = *(const float4*)(a + c0);
    const float4 a2 = *(const float4*)(a + 128 + c0);

#pragma unroll
    for (int ri = 0; ri < 4; ++ri) {
        int row = row0 + rg * 4 + ri;
        float p1 = acc[ri][0] * a1.x + acc[ri][1] * a1.y + acc[ri][2] * a1.z + acc[ri][3] * a1.w;
        float p2 = acc[ri][0] * a2.x + acc[ri][1] * a2.y + acc[ri][2] * a2.z + acc[ri][3] * a2.w;
#pragma unroll
        for (int m = 16; m >= 1; m >>= 1) {
            p1 += __shfl_xor(p1, m, 64);
            p2 += __shfl_xor(p2, m, 64);
        }
        if (row < N) {
            ushort4 hv;
            hv.x = f2b(acc[ri][0]); hv.y = f2b(acc[ri][1]);
            hv.z = f2b(acc[ri][2]); hv.w = f2b(acc[ri][3]);
            *(ushort4*)(hb + (size_t)row * DOUT + c0) = hv;
            if (cg == 0) { s1[row] = p1; s2[row] = p2; }
        }
    }
}

// ---------------------------------------------------------------------------
// K2: per-edge weight + scatter (dst, w) into padded per-node buckets.
// R7 form (one atomic/edge). R11's extra int64 wsum atomic made this 66 us
// (atomic/latency-bound, VALUBusy 1%) -> reverted; ws now summed in K3.
// ---------------------------------------------------------------------------
__global__ void scatter_kernel(
    const int* __restrict__ src, const int* __restrict__ dst,
    const float* __restrict__ s1, const float* __restrict__ s2,
    int* __restrict__ cursor, int2* __restrict__ bucket, int E)
{
    int i = blockIdx.x * blockDim.x + threadIdx.x;
    int stride = gridDim.x * blockDim.x;
    for (; i < E; i += stride) {
        int s = src[i], d = dst[i];
        float logit = s1[s] + s2[d];
        float lr = (logit > 0.f) ? logit : ALPHA * logit;
        float wv = expf(-lr);
        int pos = atomicAdd(&cursor[s], 1);
        if (pos < CAP) bucket[(size_t)s * CAP + pos] = make_int2(d, __float_as_int(wv));
    }
}

// ---------------------------------------------------------------------------
// K3: one wave per node; bf16 h gathers, 8x/2x unrolled for MLP.
// ws/ax/ay all accumulate int32 TERMS (single v_cvt_i32_f32, scale 2^24)
// into int64 accumulators: exact integer sums => bucket-order-invariant =>
// bit-deterministic. Bounds (measured scale): w <= ~11 (logit ~ N(0,4)),
// |h| <= ~5.5 -> ax-term <= 11*5.5*2^24 ~ 1.0e9 < 2^31; ws-term <= 1.8e8.
// Truncation <= 12*2^-24 ~ 7e-7, amplified <= ~100x -> ~7e-5 << 2e-3 budget.
// ---------------------------------------------------------------------------
#define EDGE(k)                                                          \
    {                                                                    \
        float wvs = __int_as_float(e##k.y) * 0x1p24f;                    \
        wsi += (long long)(int)wvs;                                      \
        axi += (long long)(int)(wvs * blo(v##k));                        \
        ayi += (long long)(int)(wvs * bhi(v##k));                        \
    }

__global__ __launch_bounds__(256) void aggregate_kernel(
    const unsigned int* __restrict__ hb, const int* __restrict__ cursor,
    const int2* __restrict__ bucket, float* __restrict__ out, int N)
{
    const int node = blockIdx.x * 4 + (threadIdx.x >> 6);
    const int lane = threadIdx.x & 63;
    if (node >= N) return;

    const int2* __restrict__ csr = bucket + (size_t)node * CAP;
    const int cnt = min(cursor[node], CAP);

    long long wsi = 0, axi = 0, ayi = 0;
    int i = 0;
    for (; i + 8 <= cnt; i += 8) {
        int2 e0 = csr[i + 0], e1 = csr[i + 1], e2 = csr[i + 2], e3 = csr[i + 3];
        int2 e4 = csr[i + 4], e5 = csr[i + 5], e6 = csr[i + 6], e7 = csr[i + 7];
        unsigned int v0 = hb[(size_t)e0.x * 64 + lane];
        unsigned int v1 = hb[(size_t)e1.x * 64 + lane];
        unsigned int v2 = hb[(size_t)e2.x * 64 + lane];
        unsigned int v3 = hb[(size_t)e3.x * 64 + lane];
        unsigned int v4 = hb[(size_t)e4.x * 64 + lane];
        unsigned int v5 = hb[(size_t)e5.x * 64 + lane];
        unsigned int v6 = hb[(size_t)e6.x * 64 + lane];
        unsigned int v7 = hb[(size_t)e7.x * 64 + lane];
        EDGE(0) EDGE(1) EDGE(2) EDGE(3) EDGE(4) EDGE(5) EDGE(6) EDGE(7)
    }
    for (; i + 2 <= cnt; i += 2) {
        int2 e0 = csr[i + 0], e1 = csr[i + 1];
        unsigned int v0 = hb[(size_t)e0.x * 64 + lane];
        unsigned int v1 = hb[(size_t)e1.x * 64 + lane];
        EDGE(0) EDGE(1)
    }
    if (i < cnt) {
        int2 e0 = csr[i];
        unsigned int v0 = hb[(size_t)e0.x * 64 + lane];
        EDGE(0)
    }

    float ws = (float)wsi * 0x1p-24f;
    float ax = (float)axi * 0x1p-24f;
    float ay = (float)ayi * 0x1p-24f;

    float inv = 1.f / fmaxf(ws, EPS);
    float ux = fmaxf(ax * inv, 0.f) * INV_SCALE;
    float uy = fmaxf(ay * inv, 0.f) * INV_SCALE;

    float nsq = ux * ux + uy * uy;
#pragma unroll
    for (int m = 32; m >= 1; m >>= 1) nsq += __shfl_xor(nsq, m, 64);
    float norm = fmaxf(sqrtf(nsq), EPS);
    float scale = tanhf(norm) / norm;

    *(float2*)(out + (size_t)node * DOUT + lane * 2) = make_float2(ux * scale, uy * scale);
}

// ---------------------------------------------------------------------------
extern "C" void kernel_launch(void* const* d_in, const int* in_sizes, int n_in,
                              void* d_out, int out_size, void* d_ws, size_t ws_size,
                              hipStream_t stream)
{
    const float* x = (const float*)d_in[0];
    const float* W = (const float*)d_in[1];
    const float* a = (const float*)d_in[2];
    const int* edge = (const int*)d_in[3];
    const int N = in_sizes[0] / DIN;
    const int E = in_sizes[3] / 2;
    const int* src = edge;
    const int* dst = edge + E;
    float* out = (float*)d_out;

    char* w = (char*)d_ws;
    size_t off = 0;
    auto take = [&](size_t bytes) -> void* {
        void* p = (void*)(w + off);
        off += (bytes + 255) & ~(size_t)255;
        return p;
    };
    unsigned short* hb = (unsigned short*)take((size_t)N * DOUT * 2);  // 12.8 MB bf16
    float* s1     = (float*)take((size_t)N * 4);
    float* s2     = (float*)take((size_t)N * 4);
    int*   cursor = (int*)  take((size_t)N * 4);
    int2*  bucket = (int2*) take((size_t)N * CAP * 8);                 // 25.6 MB
    (void)ws_size; (void)n_in; (void)out_size;

    hipLaunchKernelGGL(gemm_s_kernel, dim3((N + 31) / 32), dim3(256), 0, stream,
                       x, W, a, hb, s1, s2, cursor, N);
    hipLaunchKernelGGL(scatter_kernel, dim3(1024), dim3(256), 0, stream,
                       src, dst, s1, s2, cursor, bucket, E);
    hipLaunchKernelGGL(aggregate_kernel, dim3((N + 3) / 4), dim3(256), 0, stream,
                       (const unsigned int*)hb, cursor, bucket, out, N);
}

// Round 13
// 105.335 us; speedup vs baseline: 1.2639x; 1.0469x over previous
//
#include <hip/hip_runtime.h>
#include <hip/hip_bf16.h>
#include <hip/hip_fp16.h>

#define DIN 128
#define DOUT 128
#define ALPHA 0.2f
#define EPS 1e-15f
#define INV_SCALE 0.1f
#define KB 16
#define CAP 64   // padded bucket capacity; max degree ~28 for Binomial(600K,1/50K)

__device__ inline unsigned short f2b(float f) {
    unsigned int u = __float_as_uint(f);
    unsigned int r = (u + 0x7fffu + ((u >> 16) & 1u)) >> 16;   // RNE
    return (unsigned short)r;
}
__device__ inline float blo(unsigned int v) { return __uint_as_float(v << 16); }
__device__ inline float bhi(unsigned int v) { return __uint_as_float(v & 0xffff0000u); }

// ---------------------------------------------------------------------------
// K1: h = x @ W (fp32 accum, bf16 store), s1 = h.a[0:128], s2 = h.a[128:256].
// R7 structure (tripwire-green). Preamble zeroes cursor[].
// ---------------------------------------------------------------------------
__global__ __launch_bounds__(256) void gemm_s_kernel(
    const float* __restrict__ x, const float* __restrict__ W,
    const float* __restrict__ a, unsigned short* __restrict__ hb,
    float* __restrict__ s1, float* __restrict__ s2,
    int* __restrict__ cursor, int N)
{
    __shared__ float xT[128 * 32];        // [k][r] 16 KB
    __shared__ float Wc[2][KB * 128];     // [kk][c] 2 x 8 KB
    const int t = threadIdx.x;
    const int row0 = blockIdx.x * 32;

    {   // fused cursor zero (grid 1563*256 >= N)
        int g0 = blockIdx.x * 256 + t;
        if (g0 < N) cursor[g0] = 0;
    }

    // Load x tile transposed -> LDS
#pragma unroll
    for (int it = 0; it < 4; ++it) {
        int i = t + it * 256;
        int r = i & 31;
        int k4 = i >> 5;
        int row = row0 + r;
        float4 v = make_float4(0.f, 0.f, 0.f, 0.f);
        if (row < N) v = *(const float4*)(x + (size_t)row * DIN + k4 * 4);
        xT[(k4 * 4 + 0) * 32 + r] = v.x;
        xT[(k4 * 4 + 1) * 32 + r] = v.y;
        xT[(k4 * 4 + 2) * 32 + r] = v.z;
        xT[(k4 * 4 + 3) * 32 + r] = v.w;
    }

    auto stage = [&](int buf, int k0) {
        const float4* Wg = (const float4*)(W + k0 * 128);
        float4* Wd = (float4*)Wc[buf];
        Wd[t] = Wg[t];
        Wd[t + 256] = Wg[t + 256];
    };
    stage(0, 0);
    __syncthreads();

    const int cg = t & 31;
    const int rg = t >> 5;
    const int c0 = cg * 4;

    float acc[4][4];
#pragma unroll
    for (int i = 0; i < 4; ++i)
#pragma unroll
        for (int j = 0; j < 4; ++j) acc[i][j] = 0.f;

    const int NCH = 128 / KB;   // 8
    for (int c = 0; c < NCH; ++c) {
        if (c + 1 < NCH) stage((c + 1) & 1, (c + 1) * KB);
        const float* Wb = Wc[c & 1];
        const int kbase = c * KB;
#pragma unroll
        for (int kk = 0; kk < KB; ++kk) {
            float4 wv = *(const float4*)(Wb + kk * 128 + c0);
            float4 xv = *(const float4*)(xT + (kbase + kk) * 32 + rg * 4);
            float xr[4] = {xv.x, xv.y, xv.z, xv.w};
            float wr[4] = {wv.x, wv.y, wv.z, wv.w};
#pragma unroll
            for (int i = 0; i < 4; ++i)
#pragma unroll
                for (int j = 0; j < 4; ++j) acc[i][j] = fmaf(xr[i], wr[j], acc[i][j]);
        }
        __syncthreads();
    }

    const float4 a1 = *(const float4*)(a + c0);
    const float4 a2 = *(const float4*)(a + 128 + c0);

#pragma unroll
    for (int ri = 0; ri < 4; ++ri) {
        int row = row0 + rg * 4 + ri;
        float p1 = acc[ri][0] * a1.x + acc[ri][1] * a1.y + acc[ri][2] * a1.z + acc[ri][3] * a1.w;
        float p2 = acc[ri][0] * a2.x + acc[ri][1] * a2.y + acc[ri][2] * a2.z + acc[ri][3] * a2.w;
#pragma unroll
        for (int m = 16; m >= 1; m >>= 1) {
            p1 += __shfl_xor(p1, m, 64);
            p2 += __shfl_xor(p2, m, 64);
        }
        if (row < N) {
            ushort4 hv;
            hv.x = f2b(acc[ri][0]); hv.y = f2b(acc[ri][1]);
            hv.z = f2b(acc[ri][2]); hv.w = f2b(acc[ri][3]);
            *(ushort4*)(hb + (size_t)row * DOUT + c0) = hv;
            if (cg == 0) { s1[row] = p1; s2[row] = p2; }
        }
    }
}

// ---------------------------------------------------------------------------
// K2: per-edge weight + scatter packed 4B entries (f16 w << 16 | dst) into
// padded per-node buckets. 4B entries: node's ~12 entries fit ONE 64B line
// (R12 showed 8B entries at 25.6MB thrash L2: WRITE_SIZE 38.5MB for 4.8MB
// payload). One-edge-per-thread grid for max memory-level parallelism.
// ---------------------------------------------------------------------------
__global__ void scatter_kernel(
    const int* __restrict__ src, const int* __restrict__ dst,
    const float* __restrict__ s1, const float* __restrict__ s2,
    int* __restrict__ cursor, unsigned int* __restrict__ bucket, int E)
{
    int i = blockIdx.x * blockDim.x + threadIdx.x;
    int stride = gridDim.x * blockDim.x;
    for (; i < E; i += stride) {
        int s = src[i], d = dst[i];
        float logit = s1[s] + s2[d];
        float lr = (logit > 0.f) ? logit : ALPHA * logit;
        float wv = expf(-lr);
        unsigned int pk = ((unsigned int)__half_as_ushort(__float2half(wv)) << 16)
                        | (unsigned int)d;
        int pos = atomicAdd(&cursor[s], 1);
        if (pos < CAP) bucket[(size_t)s * CAP + pos] = pk;
    }
}

// ---------------------------------------------------------------------------
// K3: one wave per node; bf16 h gathers, 8x/2x unrolled for MLP.
// ws/ax/ay accumulate int32 TERMS (scale 2^24) into int64 accumulators:
// exact integer sums => bucket-order-invariant => bit-deterministic.
// Bounds: w <= ~11, |h| <= ~5.5 -> ax-term <= 1.0e9 < 2^31.
// ---------------------------------------------------------------------------
#define EDGE(k)                                                          \
    {                                                                    \
        float wf = __half2float(__ushort_as_half((unsigned short)(e##k >> 16))); \
        float wvs = wf * 0x1p24f;                                        \
        wsi += (long long)(int)wvs;                                      \
        axi += (long long)(int)(wvs * blo(v##k));                        \
        ayi += (long long)(int)(wvs * bhi(v##k));                        \
    }

__global__ __launch_bounds__(256) void aggregate_kernel(
    const unsigned int* __restrict__ hb, const int* __restrict__ cursor,
    const unsigned int* __restrict__ bucket, float* __restrict__ out, int N)
{
    const int node = blockIdx.x * 4 + (threadIdx.x >> 6);
    const int lane = threadIdx.x & 63;
    if (node >= N) return;

    const unsigned int* __restrict__ csr = bucket + (size_t)node * CAP;
    const int cnt = min(cursor[node], CAP);

    long long wsi = 0, axi = 0, ayi = 0;
    int i = 0;
    for (; i + 8 <= cnt; i += 8) {
        unsigned int e0 = csr[i + 0], e1 = csr[i + 1], e2 = csr[i + 2], e3 = csr[i + 3];
        unsigned int e4 = csr[i + 4], e5 = csr[i + 5], e6 = csr[i + 6], e7 = csr[i + 7];
        unsigned int v0 = hb[(size_t)(e0 & 0xffff) * 64 + lane];
        unsigned int v1 = hb[(size_t)(e1 & 0xffff) * 64 + lane];
        unsigned int v2 = hb[(size_t)(e2 & 0xffff) * 64 + lane];
        unsigned int v3 = hb[(size_t)(e3 & 0xffff) * 64 + lane];
        unsigned int v4 = hb[(size_t)(e4 & 0xffff) * 64 + lane];
        unsigned int v5 = hb[(size_t)(e5 & 0xffff) * 64 + lane];
        unsigned int v6 = hb[(size_t)(e6 & 0xffff) * 64 + lane];
        unsigned int v7 = hb[(size_t)(e7 & 0xffff) * 64 + lane];
        EDGE(0) EDGE(1) EDGE(2) EDGE(3) EDGE(4) EDGE(5) EDGE(6) EDGE(7)
    }
    for (; i + 2 <= cnt; i += 2) {
        unsigned int e0 = csr[i + 0], e1 = csr[i + 1];
        unsigned int v0 = hb[(size_t)(e0 & 0xffff) * 64 + lane];
        unsigned int v1 = hb[(size_t)(e1 & 0xffff) * 64 + lane];
        EDGE(0) EDGE(1)
    }
    if (i < cnt) {
        unsigned int e0 = csr[i];
        unsigned int v0 = hb[(size_t)(e0 & 0xffff) * 64 + lane];
        EDGE(0)
    }

    float ws = (float)wsi * 0x1p-24f;
    float ax = (float)axi * 0x1p-24f;
    float ay = (float)ayi * 0x1p-24f;

    float inv = 1.f / fmaxf(ws, EPS);
    float ux = fmaxf(ax * inv, 0.f) * INV_SCALE;
    float uy = fmaxf(ay * inv, 0.f) * INV_SCALE;

    float nsq = ux * ux + uy * uy;
#pragma unroll
    for (int m = 32; m >= 1; m >>= 1) nsq += __shfl_xor(nsq, m, 64);
    float norm = fmaxf(sqrtf(nsq), EPS);
    float scale = tanhf(norm) / norm;

    *(float2*)(out + (size_t)node * DOUT + lane * 2) = make_float2(ux * scale, uy * scale);
}

// ---------------------------------------------------------------------------
extern "C" void kernel_launch(void* const* d_in, const int* in_sizes, int n_in,
                              void* d_out, int out_size, void* d_ws, size_t ws_size,
                              hipStream_t stream)
{
    const float* x = (const float*)d_in[0];
    const float* W = (const float*)d_in[1];
    const float* a = (const float*)d_in[2];
    const int* edge = (const int*)d_in[3];
    const int N = in_sizes[0] / DIN;
    const int E = in_sizes[3] / 2;
    const int* src = edge;
    const int* dst = edge + E;
    float* out = (float*)d_out;

    char* w = (char*)d_ws;
    size_t off = 0;
    auto take = [&](size_t bytes) -> void* {
        void* p = (void*)(w + off);
        off += (bytes + 255) & ~(size_t)255;
        return p;
    };
    unsigned short* hb  = (unsigned short*)take((size_t)N * DOUT * 2);  // 12.8 MB bf16
    float*        s1     = (float*)       take((size_t)N * 4);
    float*        s2     = (float*)       take((size_t)N * 4);
    int*          cursor = (int*)         take((size_t)N * 4);
    unsigned int* bucket = (unsigned int*)take((size_t)N * CAP * 4);    // 12.8 MB
    (void)ws_size; (void)n_in; (void)out_size;

    hipLaunchKernelGGL(gemm_s_kernel, dim3((N + 31) / 32), dim3(256), 0, stream,
                       x, W, a, hb, s1, s2, cursor, N);
    hipLaunchKernelGGL(scatter_kernel, dim3((E + 255) / 256), dim3(256), 0, stream,
                       src, dst, s1, s2, cursor, bucket, E);
    hipLaunchKernelGGL(aggregate_kernel, dim3((N + 3) / 4), dim3(256), 0, stream,
                       (const unsigned int*)hb, cursor, bucket, out, N);
}